// Round 17
// baseline (274.885 us; speedup 1.0000x reference)
//
#include <hip/hip_runtime.h>
#include <math.h>

#define WIDTH 256
typedef unsigned short u16;
typedef unsigned int u32;
typedef __attribute__((ext_vector_type(4))) float f32x4;
typedef __attribute__((ext_vector_type(8))) short bf16x8;

__device__ __forceinline__ float gelu_exact(float v) {
    return 0.5f * v * (1.0f + erff(v * 0.70710678118654752f));
}
__device__ __forceinline__ u16 f2b(float x) {   // f32 -> bf16 RTNE
    u32 u = __builtin_bit_cast(u32, x);
    return (u16)((u + 0x7fffu + ((u >> 16) & 1u)) >> 16);
}
__device__ __forceinline__ float b2f_lo(u32 v) {
    return __builtin_bit_cast(float, v << 16);
}
__device__ __forceinline__ float b2f_hi(u32 v) {
    return __builtin_bit_cast(float, v & 0xffff0000u);
}
__device__ __forceinline__ float b2fu(u16 b) {
    return __builtin_bit_cast(float, ((u32)b) << 16);
}
__device__ __forceinline__ u32 pack2(float a, float b) {
    return (u32)f2b(a) | ((u32)f2b(b) << 16);
}

// ---------------- prep: WgT transpose + WfT copy + x->bf16 (no atomics) ----------------
#define PREP_WG   (4 * 65536)
#define PREP_WF   (256 * 64)
__global__ void k_prep(const float* __restrict__ Wg, const float* __restrict__ Wf,
                       const float* __restrict__ x,
                       u16* __restrict__ WgT, u16* __restrict__ WfT,
                       u16* __restrict__ xb, int total8) {
    int idx = blockIdx.x * blockDim.x + threadIdx.x;
    if (idx < PREP_WG) {
        int l = idx >> 16;
        int k = (idx >> 8) & 255;
        int n = idx & 255;
        WgT[(size_t)l * 65536 + (size_t)n * 256 + k] = f2b(Wg[idx]);
    } else if (idx < PREP_WG + PREP_WF) {
        int j = idx - PREP_WG;
        WfT[j] = f2b(Wf[j]);   // Wf already [n][k]
    } else if (idx < PREP_WG + PREP_WF + total8) {
        int i = idx - (PREP_WG + PREP_WF);
        const float4 v0 = *reinterpret_cast<const float4*>(&x[(size_t)i * 8]);
        const float4 v1 = *reinterpret_cast<const float4*>(&x[(size_t)i * 8 + 4]);
        uint4 o;
        o.x = pack2(v0.x, v0.y);
        o.y = pack2(v0.z, v0.w);
        o.z = pack2(v1.x, v1.y);
        o.w = pack2(v1.z, v1.w);
        *reinterpret_cast<uint4*>(&xb[(size_t)i * 8]) = o;
    }
}

// ---------------- hist: XCD-sharded deg count + per-edge local rank ----------------
// copy c = blockIdx&7 (~XCD under round-robin dispatch). Each copy is a private 200KB
// array -> atomics stay XCD-L2-local (no cross-XCD line bouncing). ANY block->copy
// mapping is correct: k_fill recomputes c = (i>>8)&7 deterministically.
__global__ void k_hist8(const int* __restrict__ col, int* __restrict__ deg8,
                        u16* __restrict__ rank, int E, int N) {
    int i = blockIdx.x * blockDim.x + threadIdx.x;
    if (i < E) {
        const int c = blockIdx.x & 7;
        rank[i] = (u16)atomicAdd(&deg8[(size_t)c * N + col[i]], 1);
    }
}

// per-block scan of total deg -> off (block-local) + part; also base8 (copy prefix) + dis
__global__ __launch_bounds__(256) void k_scan1(const int* __restrict__ deg8, int* __restrict__ off,
                                               int* __restrict__ part, float* __restrict__ dis,
                                               u16* __restrict__ base8, int N) {
    __shared__ int buf[256];
    const int t = threadIdx.x;
    const int gid = blockIdx.x * 256 + t;
    int d = 0;
    if (gid < N) {
        int run = 0;
#pragma unroll
        for (int c = 0; c < 8; ++c) {
            base8[(size_t)c * N + gid] = (u16)run;
            run += deg8[(size_t)c * N + gid];
        }
        d = run;
        dis[gid] = rsqrtf(1.0f + (float)run);
    }
    buf[t] = d;
    __syncthreads();
#pragma unroll
    for (int dd = 1; dd < 256; dd <<= 1) {
        int add = (t >= dd) ? buf[t - dd] : 0;
        __syncthreads();
        buf[t] += add;
        __syncthreads();
    }
    if (gid < N) off[gid] = buf[t] - d;
    if (t == 255) part[blockIdx.x] = buf[255];
}

// fused scan-of-parts + add-base (each block redundantly scans part[] in LDS)
__global__ __launch_bounds__(256) void k_scan3(int* __restrict__ off, const int* __restrict__ part,
                                               int NB, int N, int E) {
    __shared__ int buf[256];
    const int t = threadIdx.x;
    int v = (t < NB) ? part[t] : 0;
    buf[t] = v;
    __syncthreads();
#pragma unroll
    for (int d = 1; d < 256; d <<= 1) {
        int add = (t >= d) ? buf[t - d] : 0;
        __syncthreads();
        buf[t] += add;
        __syncthreads();
    }
    const int base = (blockIdx.x == 0) ? 0 : buf[blockIdx.x - 1];
    const int gid = blockIdx.x * 256 + t;
    if (gid < N) off[gid] += base;
    if (gid == 0) off[N] = E;
}

// csr entry = (src u16) | (bf16(dis[src]) << 16)
// position = off[col] + base8[copy][col] + local rank (no atomics)
__global__ void k_fill(const int* __restrict__ row, const int* __restrict__ col,
                       const u16* __restrict__ rank, const u16* __restrict__ base8,
                       const float* __restrict__ dis,
                       const int* __restrict__ off, u32* __restrict__ csr, int E, int N) {
    int i = blockIdx.x * blockDim.x + threadIdx.x;
    if (i < E) {
        const int c = blockIdx.x & 7;
        const int r = row[i];
        const int cc = col[i];
        const int pos = off[cc] + (int)base8[(size_t)c * N + cc] + (int)rank[i];
        csr[pos] = (u32)(u16)r | ((u32)f2b(dis[r]) << 16);
    }
}

// ---------------- frontier F1: list1 = dedup( centers U in-neighbors(centers) ) ----------------
__global__ void k_front(const int* __restrict__ center, const int* __restrict__ ptr,
                        const int* __restrict__ off, const u32* __restrict__ csr,
                        int* __restrict__ flags, int* __restrict__ list, int* __restrict__ cnt) {
    const int g = blockIdx.x;
    const int node = center[g] + ptr[g];
    const int t = threadIdx.x;
    const int e0 = off[node];
    const int e1 = off[node + 1];
    if (t == 0) {
        if (atomicExch(&flags[node], 1) == 0) list[atomicAdd(cnt, 1)] = node;
    }
    for (int e = e0 + t; e < e1; e += 256) {
        const int s = (int)(csr[e] & 0xffffu);
        if (atomicExch(&flags[s], 1) == 0) list[atomicAdd(cnt, 1)] = s;
    }
}

// ---------------- frontier F2: list2 = dedup( F1 U in-neighbors(F1) ) ----------------
__global__ void k_front2(const int* __restrict__ off, const u32* __restrict__ csr,
                         const int* __restrict__ list1, const int* __restrict__ cnt1,
                         int* __restrict__ flags2, int* __restrict__ list2, int* __restrict__ cnt2) {
    const int n1 = cnt1[0];
    const int t = threadIdx.x;
    for (int idx = blockIdx.x; idx < n1; idx += gridDim.x) {
        const int node = list1[idx];
        if (t == 0) {
            if (atomicExch(&flags2[node], 1) == 0) list2[atomicAdd(cnt2, 1)] = node;
        }
        const int e0 = off[node];
        const int e1 = off[node + 1];
        for (int e = e0 + t; e < e1; e += 256) {
            const int s = (int)(csr[e] & 0xffffu);
            if (atomicExch(&flags2[s], 1) == 0) list2[atomicAdd(cnt2, 1)] = s;
        }
    }
}

// ---------------- MFMA GEMM v3: 128x256 tile, 8 waves (round-14 verified) ----------------
template <int KDIM, bool FOOT>
__global__ __launch_bounds__(512) void k_gemm_mfma(const u16* __restrict__ A,
                                                   const u16* __restrict__ BT,
                                                   const float* __restrict__ bias,
                                                   u16* __restrict__ Cb,
                                                   float* __restrict__ Cf, int nrows) {
    __shared__ u16 As[128 * 64];   // 16 KB
    __shared__ u16 Bs[256 * 64];   // 32 KB

    const int tid = threadIdx.x;
    const int w = tid >> 6;        // 0..7
    const int l = tid & 63;
    const int m0 = blockIdx.x * 128;
    const int wr = w >> 2;         // row half
    const int wc = w & 3;          // col quarter

    const int lr = l >> 3;
    const int lc = l & 7;
    const int src_slot = lc ^ lr;

    f32x4 acc[4][4] = {};

#pragma unroll
    for (int ks = 0; ks < KDIM / 64; ++ks) {
        const int k0 = ks * 64;
#pragma unroll
        for (int i = 0; i < 2; ++i) {
            const u16* asrc = A + (size_t)(m0 + 16 * w + 8 * i + lr) * KDIM + k0 + src_slot * 8;
            __builtin_amdgcn_global_load_lds(
                (const __attribute__((address_space(1))) u32*)asrc,
                (__attribute__((address_space(3))) u32*)(As + (16 * w + 8 * i) * 64), 16, 0, 0);
        }
#pragma unroll
        for (int j = 0; j < 4; ++j) {
            const u16* bsrc = BT + (size_t)(32 * w + 8 * j + lr) * KDIM + k0 + src_slot * 8;
            __builtin_amdgcn_global_load_lds(
                (const __attribute__((address_space(1))) u32*)bsrc,
                (__attribute__((address_space(3))) u32*)(Bs + (32 * w + 8 * j) * 64), 16, 0, 0);
        }
        asm volatile("s_waitcnt vmcnt(0)" ::: "memory");
        __syncthreads();

        bf16x8 a[4][2], b[4][2];
#pragma unroll
        for (int fr = 0; fr < 4; ++fr) {
            const int row = 64 * wr + fr * 16 + (l & 15);
#pragma unroll
            for (int kk = 0; kk < 2; ++kk)
                a[fr][kk] = *reinterpret_cast<const bf16x8*>(
                    &As[row * 64 + ((kk * 4 + (l >> 4)) ^ (row & 7)) * 8]);
        }
#pragma unroll
        for (int fc = 0; fc < 4; ++fc) {
            const int row = 64 * wc + fc * 16 + (l & 15);
#pragma unroll
            for (int kk = 0; kk < 2; ++kk)
                b[fc][kk] = *reinterpret_cast<const bf16x8*>(
                    &Bs[row * 64 + ((kk * 4 + (l >> 4)) ^ (row & 7)) * 8]);
        }
#pragma unroll
        for (int fr = 0; fr < 4; ++fr)
#pragma unroll
            for (int fc = 0; fc < 4; ++fc) {
                acc[fr][fc] = __builtin_amdgcn_mfma_f32_16x16x32_bf16(a[fr][0], b[fc][0], acc[fr][fc], 0, 0, 0);
                acc[fr][fc] = __builtin_amdgcn_mfma_f32_16x16x32_bf16(a[fr][1], b[fc][1], acc[fr][fc], 0, 0, 0);
            }
        __syncthreads();
    }

    const int r0 = (l >> 4) * 4;
    const int ci = l & 15;
#pragma unroll
    for (int fr = 0; fr < 4; ++fr)
#pragma unroll
        for (int fc = 0; fc < 4; ++fc) {
            const int col = 64 * wc + fc * 16 + ci;
#pragma unroll
            for (int r = 0; r < 4; ++r) {
                const int row = m0 + 64 * wr + fr * 16 + r0 + r;
                if (row < nrows) {
                    const size_t p = (size_t)row * WIDTH + col;
                    if (FOOT) {
                        const float o = gelu_exact(acc[fr][fc][r] + bias[col]);
                        Cf[p] = o;
                        Cb[p] = f2b(o);
                    } else {
                        Cb[p] = f2b(acc[fr][fc][r]);
                    }
                }
            }
        }
}

// ---------------- gather-GEMM (layer 2): rows from list, grid-stride ----------------
// xlb[list[r]] = hb[list[r]] @ Wg; only F2 rows are ever consumed downstream.
__global__ __launch_bounds__(512) void k_gemm_gather(const u16* __restrict__ A,
                                                     const u16* __restrict__ BT,
                                                     u16* __restrict__ Cb,
                                                     const int* __restrict__ list,
                                                     const int* __restrict__ cnt) {
    __shared__ u16 As[128 * 64];
    __shared__ u16 Bs[256 * 64];

    const int nrows = cnt[0];
    const int tid = threadIdx.x;
    const int w = tid >> 6;
    const int l = tid & 63;
    const int wr = w >> 2;
    const int wc = w & 3;

    const int lr = l >> 3;
    const int lc = l & 7;
    const int src_slot = lc ^ lr;

    for (int m0 = blockIdx.x * 128; m0 < nrows; m0 += gridDim.x * 128) {
        f32x4 acc[4][4] = {};

#pragma unroll
        for (int ks = 0; ks < 4; ++ks) {
            const int k0 = ks * 64;
#pragma unroll
            for (int i = 0; i < 2; ++i) {
                int ridx = m0 + 16 * w + 8 * i + lr;
                ridx = min(ridx, nrows - 1);
                const u16* asrc = A + (size_t)list[ridx] * WIDTH + k0 + src_slot * 8;
                __builtin_amdgcn_global_load_lds(
                    (const __attribute__((address_space(1))) u32*)asrc,
                    (__attribute__((address_space(3))) u32*)(As + (16 * w + 8 * i) * 64), 16, 0, 0);
            }
#pragma unroll
            for (int j = 0; j < 4; ++j) {
                const u16* bsrc = BT + (size_t)(32 * w + 8 * j + lr) * WIDTH + k0 + src_slot * 8;
                __builtin_amdgcn_global_load_lds(
                    (const __attribute__((address_space(1))) u32*)bsrc,
                    (__attribute__((address_space(3))) u32*)(Bs + (32 * w + 8 * j) * 64), 16, 0, 0);
            }
            asm volatile("s_waitcnt vmcnt(0)" ::: "memory");
            __syncthreads();

            bf16x8 a[4][2], b[4][2];
#pragma unroll
            for (int fr = 0; fr < 4; ++fr) {
                const int row = 64 * wr + fr * 16 + (l & 15);
#pragma unroll
                for (int kk = 0; kk < 2; ++kk)
                    a[fr][kk] = *reinterpret_cast<const bf16x8*>(
                        &As[row * 64 + ((kk * 4 + (l >> 4)) ^ (row & 7)) * 8]);
            }
#pragma unroll
            for (int fc = 0; fc < 4; ++fc) {
                const int row = 64 * wc + fc * 16 + (l & 15);
#pragma unroll
                for (int kk = 0; kk < 2; ++kk)
                    b[fc][kk] = *reinterpret_cast<const bf16x8*>(
                        &Bs[row * 64 + ((kk * 4 + (l >> 4)) ^ (row & 7)) * 8]);
            }
#pragma unroll
            for (int fr = 0; fr < 4; ++fr)
#pragma unroll
                for (int fc = 0; fc < 4; ++fc) {
                    acc[fr][fc] = __builtin_amdgcn_mfma_f32_16x16x32_bf16(a[fr][0], b[fc][0], acc[fr][fc], 0, 0, 0);
                    acc[fr][fc] = __builtin_amdgcn_mfma_f32_16x16x32_bf16(a[fr][1], b[fc][1], acc[fr][fc], 0, 0, 0);
                }
            __syncthreads();
        }

        const int r0 = (l >> 4) * 4;
        const int ci = l & 15;
#pragma unroll
        for (int fr = 0; fr < 4; ++fr)
#pragma unroll
            for (int fc = 0; fc < 4; ++fc) {
                const int col = 64 * wc + fc * 16 + ci;
#pragma unroll
                for (int r = 0; r < 4; ++r) {
                    const int row = m0 + 64 * wr + fr * 16 + r0 + r;
                    if (row < nrows)
                        Cb[(size_t)list[row] * WIDTH + col] = f2b(acc[fr][fc][r]);
                }
            }
    }
}

#define EDGE_FMA(vv, dd_)                          \
    acc[0] = fmaf(dd_, b2f_lo(vv.x), acc[0]);      \
    acc[1] = fmaf(dd_, b2f_hi(vv.x), acc[1]);      \
    acc[2] = fmaf(dd_, b2f_lo(vv.y), acc[2]);      \
    acc[3] = fmaf(dd_, b2f_hi(vv.y), acc[3]);

__device__ __forceinline__ void agg_node_body(const int* __restrict__ off,
                                              const u32* __restrict__ csr,
                                              const float* __restrict__ dis,
                                              const u16* __restrict__ xlb,
                                              const float* __restrict__ bg,
                                              float* __restrict__ h,
                                              u16* __restrict__ hb,
                                              int node, int hl, int ch0) {
    const int c = ch0 + hl * 4;
    const int e0 = off[node];
    const int e1 = off[node + 1];
    const float di = dis[node];

    float acc[4];
    // self-loop
    {
        const uint2 v = *reinterpret_cast<const uint2*>(&xlb[(size_t)node * WIDTH + c]);
        acc[0] = di * b2f_lo(v.x);
        acc[1] = di * b2f_hi(v.x);
        acc[2] = di * b2f_lo(v.y);
        acc[3] = di * b2f_hi(v.y);
    }

    for (int base = e0; base < e1; base += 32) {
        const int m = min(32, e1 - base);
        u32 ep = 0;
        if (hl < m) ep = csr[base + hl];
        int j = 0;
        for (; j + 8 <= m; j += 8) {
            uint2 vv[8];
            float dd[8];
#pragma unroll
            for (int q = 0; q < 8; ++q) {
                const u32 e = (u32)__shfl((int)ep, j + q, 32);
                dd[q] = b2f_hi(e);
                vv[q] = *reinterpret_cast<const uint2*>(&xlb[(size_t)(e & 0xffffu) * WIDTH + c]);
            }
#pragma unroll
            for (int q = 0; q < 8; ++q) { EDGE_FMA(vv[q], dd[q]) }
        }
        if (j + 4 <= m) {
            uint2 vv[4];
            float dd[4];
#pragma unroll
            for (int q = 0; q < 4; ++q) {
                const u32 e = (u32)__shfl((int)ep, j + q, 32);
                dd[q] = b2f_hi(e);
                vv[q] = *reinterpret_cast<const uint2*>(&xlb[(size_t)(e & 0xffffu) * WIDTH + c]);
            }
#pragma unroll
            for (int q = 0; q < 4; ++q) { EDGE_FMA(vv[q], dd[q]) }
            j += 4;
        }
        for (; j < m; ++j) {
            const u32 e = (u32)__shfl((int)ep, j, 32);
            const float dj = b2f_hi(e);
            const uint2 v = *reinterpret_cast<const uint2*>(&xlb[(size_t)(e & 0xffffu) * WIDTH + c]);
            EDGE_FMA(v, dj)
        }
    }

    const size_t p = (size_t)node * WIDTH + c;
    const float4 hv = *reinterpret_cast<const float4*>(&h[p]);
    const float4 bv = *reinterpret_cast<const float4*>(&bg[c]);
    const float o0 = hv.x + bv.x + di * acc[0];
    const float o1 = hv.y + bv.y + di * acc[1];
    const float o2 = hv.z + bv.z + di * acc[2];
    const float o3 = hv.w + bv.w + di * acc[3];
    float4 w0;
    w0.x = o0; w0.y = o1; w0.z = o2; w0.w = o3;
    *reinterpret_cast<float4*>(&h[p]) = w0;
    uint2 ob;
    ob.x = pack2(o0, o1);
    ob.y = pack2(o2, o3);
    *reinterpret_cast<uint2*>(&hb[p]) = ob;
}

// ---------------- full aggregate (layer 0): channel-split, both halves one dispatch ----------------
__global__ __launch_bounds__(256) void k_agg(const int* __restrict__ off,
                                             const u32* __restrict__ csr,
                                             const float* __restrict__ dis,
                                             const u16* __restrict__ xlb,
                                             const float* __restrict__ bg,
                                             float* __restrict__ h,
                                             u16* __restrict__ hb, int nbh, int N) {
    int bh = blockIdx.x;
    int ch0 = 0;
    if (bh >= nbh) { ch0 = 128; bh -= nbh; }
    const int node = (bh * 256 + threadIdx.x) >> 5;
    if (node >= N) return;
    agg_node_body(off, csr, dis, xlb, bg, h, hb, node, threadIdx.x & 31, ch0);
}

// ---------------- list aggregate (layers 1,2): grid-stride over frontier list x 2 halves ----------------
__global__ __launch_bounds__(256) void k_agg_list(const int* __restrict__ off,
                                                  const u32* __restrict__ csr,
                                                  const float* __restrict__ dis,
                                                  const u16* __restrict__ xlb,
                                                  const float* __restrict__ bg,
                                                  float* __restrict__ h,
                                                  u16* __restrict__ hb,
                                                  const int* __restrict__ list,
                                                  const int* __restrict__ cnt) {
    const int nitems = cnt[0] * 2;
    const int hl = threadIdx.x & 31;
    const int stride = (gridDim.x * 256) >> 5;
    for (int item = (blockIdx.x * 256 + threadIdx.x) >> 5; item < nitems; item += stride) {
        const int node = list[item >> 1];
        const int ch0 = (item & 1) << 7;
        agg_node_body(off, csr, dis, xlb, bg, h, hb, node, hl, ch0);
    }
}
#undef EDGE_FMA

// ---------------- fused tail: last GCN layer at the 32 centers + head ----------------
__global__ __launch_bounds__(256) void k_tail(const int* __restrict__ off,
                                              const u32* __restrict__ csr,
                                              const float* __restrict__ dis,
                                              const u16* __restrict__ hb,
                                              const float* __restrict__ h,
                                              const float* __restrict__ Wg3,
                                              const float* __restrict__ bg3,
                                              const float* __restrict__ Wh,
                                              const float* __restrict__ bh,
                                              const int* __restrict__ center,
                                              const int* __restrict__ ptr,
                                              float* __restrict__ out) {
    __shared__ float aggK[256];
    __shared__ u32 es[256];
    __shared__ float gs[256];
    const int g = blockIdx.x;
    const int t = threadIdx.x;
    const int node = center[g] + ptr[g];
    const int e0 = off[node];
    const int e1 = off[node + 1];
    const float di = dis[node];

    float acc = di * b2fu(hb[(size_t)node * WIDTH + t]);   // self-loop
    for (int base = e0; base < e1; base += 256) {
        const int m = min(256, e1 - base);
        if (t < m) es[t] = csr[base + t];
        __syncthreads();
        int j = 0;
        for (; j + 4 <= m; j += 4) {
            const u32 a0 = es[j + 0], a1 = es[j + 1], a2 = es[j + 2], a3 = es[j + 3];
            const float v0 = b2fu(hb[(size_t)(a0 & 0xffffu) * WIDTH + t]);
            const float v1 = b2fu(hb[(size_t)(a1 & 0xffffu) * WIDTH + t]);
            const float v2 = b2fu(hb[(size_t)(a2 & 0xffffu) * WIDTH + t]);
            const float v3 = b2fu(hb[(size_t)(a3 & 0xffffu) * WIDTH + t]);
            acc = fmaf(b2f_hi(a0), v0, acc);
            acc = fmaf(b2f_hi(a1), v1, acc);
            acc = fmaf(b2f_hi(a2), v2, acc);
            acc = fmaf(b2f_hi(a3), v3, acc);
        }
        for (; j < m; ++j) {
            const u32 a = es[j];
            acc = fmaf(b2f_hi(a), b2fu(hb[(size_t)(a & 0xffffu) * WIDTH + t]), acc);
        }
        __syncthreads();
    }
    aggK[t] = acc;
    __syncthreads();

    float mv = 0.0f;
#pragma unroll 8
    for (int k = 0; k < 256; ++k)
        mv = fmaf(aggK[k], Wg3[(size_t)k * 256 + t], mv);
    const float h4 = h[(size_t)node * WIDTH + t] + bg3[t] + di * mv;
    gs[t] = gelu_exact(h4);
    __syncthreads();
    if (t < 7) {
        float o = bh[t];
        for (int k = 0; k < 256; ++k)
            o = fmaf(gs[k], Wh[t * 256 + k], o);
        out[g * 7 + t] = o;
    }
}

extern "C" void kernel_launch(void* const* d_in, const int* in_sizes, int n_in,
                              void* d_out, int out_size, void* d_ws, size_t ws_size,
                              hipStream_t stream) {
    const float* x      = (const float*)d_in[0];
    const int*   ei     = (const int*)d_in[1];
    const int*   center = (const int*)d_in[2];
    const int*   ptr    = (const int*)d_in[3];
    const float* Wf     = (const float*)d_in[4];
    const float* bf     = (const float*)d_in[5];
    const float* Wg     = (const float*)d_in[6];
    const float* bg     = (const float*)d_in[7];
    const float* Wh     = (const float*)d_in[8];
    const float* bh     = (const float*)d_in[9];

    const int E = in_sizes[1] / 2;       // 799744
    const int N = in_sizes[0] / 64;      // 49984
    const int B = in_sizes[2];           // 32

    char* ws = (char*)d_ws;
    size_t o = 0;
    float* h       = (float*)(ws + o); o += (size_t)N * WIDTH * 4;   // 51.2 MB
    u16*   hb      = (u16*)  (ws + o); o += (size_t)N * WIDTH * 2;   // 25.6 MB
    u16*   xlb     = (u16*)  (ws + o); o += (size_t)N * WIDTH * 2;   // 25.6 MB
    u16*   xb      = (u16*)  (ws + o); o += (size_t)N * 64 * 2;      // 6.4 MB
    float* dis     = (float*)(ws + o); o += (size_t)N * 4;
    int*   deg8    = (int*)  (ws + o); o += (size_t)N * 8 * 4;       // 1.6 MB (8 copies)
    u16*   base8   = (u16*)  (ws + o); o += (size_t)N * 8 * 2;       // 0.8 MB
    int*   off     = (int*)  (ws + o); o += (size_t)(N + 1) * 4;
    int*   part    = (int*)  (ws + o); o += 1024;
    u16*   rank    = (u16*)  (ws + o); o += (size_t)E * 2;           // 1.6 MB
    u32*   csr     = (u32*)  (ws + o); o += (size_t)E * 4;           // 3.2 MB
    u16*   WgT     = (u16*)  (ws + o); o += (size_t)4 * 65536 * 2;   // 0.5 MB
    u16*   WfT     = (u16*)  (ws + o); o += (size_t)256 * 64 * 2;    // 32 KB
    int*   flags   = (int*)  (ws + o); o += (size_t)N * 4;           // F1 flags
    int*   flags2  = (int*)  (ws + o); o += (size_t)N * 4;           // F2 flags
    int*   cnt     = (int*)  (ws + o); o += 128;                     // F1 count
    int*   cnt2    = (int*)  (ws + o); o += 128;                     // F2 count
    int*   list1   = (int*)  (ws + o); o += (size_t)N * 4;           // F1 list
    int*   list2   = (int*)  (ws + o); o += (size_t)N * 4;           // F2 list

    const int* rowv = ei;
    const int* colv = ei + E;

    const int nb = (N + 255) / 256;   // 196
    const int eb = (E + 255) / 256;

    // CSR build: memset deg8 + frontier state -> prep || hist8 -> scans -> fill (no atomics)
    hipMemsetAsync(deg8, 0, (size_t)N * 8 * 4, stream);
    hipMemsetAsync(flags, 0, (size_t)N * 8 + 256, stream);   // flags | flags2 | cnt | cnt2
    const int total8 = N * 64 / 8;
    const int prep_threads = PREP_WG + PREP_WF + total8;
    k_prep<<<(prep_threads + 255) / 256, 256, 0, stream>>>(Wg, Wf, x, WgT, WfT, xb, total8);
    k_hist8<<<eb, 256, 0, stream>>>(colv, deg8, rank, E, N);
    k_scan1<<<nb, 256, 0, stream>>>(deg8, off, part, dis, base8, N);
    k_scan3<<<nb, 256, 0, stream>>>(off, part, nb, N, E);
    k_fill<<<eb, 256, 0, stream>>>(rowv, colv, rank, base8, dis, off, csr, E, N);
    // frontier lists: F1 = centers U N(centers); F2 = F1 U N(F1)
    k_front<<<B, 256, 0, stream>>>(center, ptr, off, csr, flags, list1, cnt);
    k_front2<<<64, 256, 0, stream>>>(off, csr, list1, cnt, flags2, list2, cnt2);

    // foot: h = gelu(xb @ WfT^T + bf); writes h f32 + hb bf16
    const int gb = (N + 127) / 128;   // 391
    k_gemm_mfma<64, true><<<gb, 512, 0, stream>>>(xb, WfT, bf, hb, h, N);

    // layer 0: full GEMM + full aggregate (hb1 needed at ~94% of nodes)
    const int nbh = N / 8;   // blocks per channel half
    k_gemm_mfma<256, false><<<gb, 512, 0, stream>>>(hb, WgT, nullptr, xlb, nullptr, N);
    k_agg<<<2 * nbh, 256, 0, stream>>>(off, csr, dis, xlb, bg, h, hb, nbh, N);

    // layer 1: full GEMM, aggregate only at F2 (h2/hb2 consumed only there)
    k_gemm_mfma<256, false><<<gb, 512, 0, stream>>>(hb, WgT + (size_t)1 * 65536, nullptr, xlb, nullptr, N);
    k_agg_list<<<1024, 256, 0, stream>>>(off, csr, dis, xlb, bg + (size_t)1 * WIDTH, h, hb, list2, cnt2);

    // layer 2: gather-GEMM over F2 rows only, aggregate only at F1
    k_gemm_gather<<<128, 512, 0, stream>>>(hb, WgT + (size_t)2 * 65536, xlb, list2, cnt2);
    k_agg_list<<<256, 256, 0, stream>>>(off, csr, dis, xlb, bg + (size_t)2 * WIDTH, h, hb, list1, cnt);

    // layer 3 + head fused at the 32 centers (f32 Wg3 matvec — no WgT/xlb/agg needed)
    k_tail<<<B, 256, 0, stream>>>(off, csr, dis, hb, h,
                                  Wg + (size_t)3 * 65536, bg + (size_t)3 * WIDTH,
                                  Wh, bh, center, ptr, (float*)d_out);
}

// Round 18
// 272.366 us; speedup vs baseline: 1.0092x; 1.0092x over previous
//
#include <hip/hip_runtime.h>
#include <math.h>

#define WIDTH 256
typedef unsigned short u16;
typedef unsigned int u32;
typedef __attribute__((ext_vector_type(4))) float f32x4;
typedef __attribute__((ext_vector_type(8))) short bf16x8;

__device__ __forceinline__ float gelu_exact(float v) {
    return 0.5f * v * (1.0f + erff(v * 0.70710678118654752f));
}
__device__ __forceinline__ u16 f2b(float x) {   // f32 -> bf16 RTNE
    u32 u = __builtin_bit_cast(u32, x);
    return (u16)((u + 0x7fffu + ((u >> 16) & 1u)) >> 16);
}
__device__ __forceinline__ float b2f_lo(u32 v) {
    return __builtin_bit_cast(float, v << 16);
}
__device__ __forceinline__ float b2f_hi(u32 v) {
    return __builtin_bit_cast(float, v & 0xffff0000u);
}
__device__ __forceinline__ float b2fu(u16 b) {
    return __builtin_bit_cast(float, ((u32)b) << 16);
}
__device__ __forceinline__ u32 pack2(float a, float b) {
    return (u32)f2b(a) | ((u32)f2b(b) << 16);
}

// ---------------- prep: WgT transpose + WfT copy + x->bf16 (no atomics) ----------------
#define PREP_WG   (4 * 65536)
#define PREP_WF   (256 * 64)
__global__ void k_prep(const float* __restrict__ Wg, const float* __restrict__ Wf,
                       const float* __restrict__ x,
                       u16* __restrict__ WgT, u16* __restrict__ WfT,
                       u16* __restrict__ xb, int total8) {
    int idx = blockIdx.x * blockDim.x + threadIdx.x;
    if (idx < PREP_WG) {
        int l = idx >> 16;
        int k = (idx >> 8) & 255;
        int n = idx & 255;
        WgT[(size_t)l * 65536 + (size_t)n * 256 + k] = f2b(Wg[idx]);
    } else if (idx < PREP_WG + PREP_WF) {
        int j = idx - PREP_WG;
        WfT[j] = f2b(Wf[j]);   // Wf already [n][k]
    } else if (idx < PREP_WG + PREP_WF + total8) {
        int i = idx - (PREP_WG + PREP_WF);
        const float4 v0 = *reinterpret_cast<const float4*>(&x[(size_t)i * 8]);
        const float4 v1 = *reinterpret_cast<const float4*>(&x[(size_t)i * 8 + 4]);
        uint4 o;
        o.x = pack2(v0.x, v0.y);
        o.y = pack2(v0.z, v0.w);
        o.z = pack2(v1.x, v1.y);
        o.w = pack2(v1.z, v1.w);
        *reinterpret_cast<uint4*>(&xb[(size_t)i * 8]) = o;
    }
}

// ---------------- hist: XCD-sharded deg count + per-edge local rank ----------------
__global__ void k_hist8(const int* __restrict__ col, int* __restrict__ deg8,
                        u16* __restrict__ rank, int E, int N) {
    int i = blockIdx.x * blockDim.x + threadIdx.x;
    if (i < E) {
        const int c = blockIdx.x & 7;
        rank[i] = (u16)atomicAdd(&deg8[(size_t)c * N + col[i]], 1);
    }
}

// per-block scan of total deg -> off (block-local) + part; also base8 (copy prefix) + dis
__global__ __launch_bounds__(256) void k_scan1(const int* __restrict__ deg8, int* __restrict__ off,
                                               int* __restrict__ part, float* __restrict__ dis,
                                               u16* __restrict__ base8, int N) {
    __shared__ int buf[256];
    const int t = threadIdx.x;
    const int gid = blockIdx.x * 256 + t;
    int d = 0;
    if (gid < N) {
        int run = 0;
#pragma unroll
        for (int c = 0; c < 8; ++c) {
            base8[(size_t)c * N + gid] = (u16)run;
            run += deg8[(size_t)c * N + gid];
        }
        d = run;
        dis[gid] = rsqrtf(1.0f + (float)run);
    }
    buf[t] = d;
    __syncthreads();
#pragma unroll
    for (int dd = 1; dd < 256; dd <<= 1) {
        int add = (t >= dd) ? buf[t - dd] : 0;
        __syncthreads();
        buf[t] += add;
        __syncthreads();
    }
    if (gid < N) off[gid] = buf[t] - d;
    if (t == 255) part[blockIdx.x] = buf[255];
}

// fused scan-of-parts + add-base
__global__ __launch_bounds__(256) void k_scan3(int* __restrict__ off, const int* __restrict__ part,
                                               int NB, int N, int E) {
    __shared__ int buf[256];
    const int t = threadIdx.x;
    int v = (t < NB) ? part[t] : 0;
    buf[t] = v;
    __syncthreads();
#pragma unroll
    for (int d = 1; d < 256; d <<= 1) {
        int add = (t >= d) ? buf[t - d] : 0;
        __syncthreads();
        buf[t] += add;
        __syncthreads();
    }
    const int base = (blockIdx.x == 0) ? 0 : buf[blockIdx.x - 1];
    const int gid = blockIdx.x * 256 + t;
    if (gid < N) off[gid] += base;
    if (gid == 0) off[N] = E;
}

// csr entry = (src u16) | (bf16(dis[src]) << 16)
__global__ void k_fill(const int* __restrict__ row, const int* __restrict__ col,
                       const u16* __restrict__ rank, const u16* __restrict__ base8,
                       const float* __restrict__ dis,
                       const int* __restrict__ off, u32* __restrict__ csr, int E, int N) {
    int i = blockIdx.x * blockDim.x + threadIdx.x;
    if (i < E) {
        const int c = blockIdx.x & 7;
        const int r = row[i];
        const int cc = col[i];
        const int pos = off[cc] + (int)base8[(size_t)c * N + cc] + (int)rank[i];
        csr[pos] = (u32)(u16)r | ((u32)f2b(dis[r]) << 16);
    }
}

// ---------------- frontier F1 ----------------
__global__ void k_front(const int* __restrict__ center, const int* __restrict__ ptr,
                        const int* __restrict__ off, const u32* __restrict__ csr,
                        int* __restrict__ flags, int* __restrict__ list, int* __restrict__ cnt) {
    const int g = blockIdx.x;
    const int node = center[g] + ptr[g];
    const int t = threadIdx.x;
    const int e0 = off[node];
    const int e1 = off[node + 1];
    if (t == 0) {
        if (atomicExch(&flags[node], 1) == 0) list[atomicAdd(cnt, 1)] = node;
    }
    for (int e = e0 + t; e < e1; e += 256) {
        const int s = (int)(csr[e] & 0xffffu);
        if (atomicExch(&flags[s], 1) == 0) list[atomicAdd(cnt, 1)] = s;
    }
}

// ---------------- frontier F2 ----------------
__global__ void k_front2(const int* __restrict__ off, const u32* __restrict__ csr,
                         const int* __restrict__ list1, const int* __restrict__ cnt1,
                         int* __restrict__ flags2, int* __restrict__ list2, int* __restrict__ cnt2) {
    const int n1 = cnt1[0];
    const int t = threadIdx.x;
    for (int idx = blockIdx.x; idx < n1; idx += gridDim.x) {
        const int node = list1[idx];
        if (t == 0) {
            if (atomicExch(&flags2[node], 1) == 0) list2[atomicAdd(cnt2, 1)] = node;
        }
        const int e0 = off[node];
        const int e1 = off[node + 1];
        for (int e = e0 + t; e < e1; e += 256) {
            const int s = (int)(csr[e] & 0xffffu);
            if (atomicExch(&flags2[s], 1) == 0) list2[atomicAdd(cnt2, 1)] = s;
        }
    }
}

// ---------------- MFMA GEMM v3: 128x256 tile, 8 waves (round-14 verified) ----------------
template <int KDIM, bool FOOT>
__global__ __launch_bounds__(512) void k_gemm_mfma(const u16* __restrict__ A,
                                                   const u16* __restrict__ BT,
                                                   const float* __restrict__ bias,
                                                   u16* __restrict__ Cb,
                                                   float* __restrict__ Cf, int nrows) {
    __shared__ u16 As[128 * 64];   // 16 KB
    __shared__ u16 Bs[256 * 64];   // 32 KB

    const int tid = threadIdx.x;
    const int w = tid >> 6;        // 0..7
    const int l = tid & 63;
    const int m0 = blockIdx.x * 128;
    const int wr = w >> 2;         // row half
    const int wc = w & 3;          // col quarter

    const int lr = l >> 3;
    const int lc = l & 7;
    const int src_slot = lc ^ lr;

    f32x4 acc[4][4] = {};

#pragma unroll
    for (int ks = 0; ks < KDIM / 64; ++ks) {
        const int k0 = ks * 64;
#pragma unroll
        for (int i = 0; i < 2; ++i) {
            const u16* asrc = A + (size_t)(m0 + 16 * w + 8 * i + lr) * KDIM + k0 + src_slot * 8;
            __builtin_amdgcn_global_load_lds(
                (const __attribute__((address_space(1))) u32*)asrc,
                (__attribute__((address_space(3))) u32*)(As + (16 * w + 8 * i) * 64), 16, 0, 0);
        }
#pragma unroll
        for (int j = 0; j < 4; ++j) {
            const u16* bsrc = BT + (size_t)(32 * w + 8 * j + lr) * KDIM + k0 + src_slot * 8;
            __builtin_amdgcn_global_load_lds(
                (const __attribute__((address_space(1))) u32*)bsrc,
                (__attribute__((address_space(3))) u32*)(Bs + (32 * w + 8 * j) * 64), 16, 0, 0);
        }
        asm volatile("s_waitcnt vmcnt(0)" ::: "memory");
        __syncthreads();

        bf16x8 a[4][2], b[4][2];
#pragma unroll
        for (int fr = 0; fr < 4; ++fr) {
            const int row = 64 * wr + fr * 16 + (l & 15);
#pragma unroll
            for (int kk = 0; kk < 2; ++kk)
                a[fr][kk] = *reinterpret_cast<const bf16x8*>(
                    &As[row * 64 + ((kk * 4 + (l >> 4)) ^ (row & 7)) * 8]);
        }
#pragma unroll
        for (int fc = 0; fc < 4; ++fc) {
            const int row = 64 * wc + fc * 16 + (l & 15);
#pragma unroll
            for (int kk = 0; kk < 2; ++kk)
                b[fc][kk] = *reinterpret_cast<const bf16x8*>(
                    &Bs[row * 64 + ((kk * 4 + (l >> 4)) ^ (row & 7)) * 8]);
        }
#pragma unroll
        for (int fr = 0; fr < 4; ++fr)
#pragma unroll
            for (int fc = 0; fc < 4; ++fc) {
                acc[fr][fc] = __builtin_amdgcn_mfma_f32_16x16x32_bf16(a[fr][0], b[fc][0], acc[fr][fc], 0, 0, 0);
                acc[fr][fc] = __builtin_amdgcn_mfma_f32_16x16x32_bf16(a[fr][1], b[fc][1], acc[fr][fc], 0, 0, 0);
            }
        __syncthreads();
    }

    const int r0 = (l >> 4) * 4;
    const int ci = l & 15;
#pragma unroll
    for (int fr = 0; fr < 4; ++fr)
#pragma unroll
        for (int fc = 0; fc < 4; ++fc) {
            const int col = 64 * wc + fc * 16 + ci;
#pragma unroll
            for (int r = 0; r < 4; ++r) {
                const int row = m0 + 64 * wr + fr * 16 + r0 + r;
                if (row < nrows) {
                    const size_t p = (size_t)row * WIDTH + col;
                    if (FOOT) {
                        const float o = gelu_exact(acc[fr][fc][r] + bias[col]);
                        Cf[p] = o;
                        Cb[p] = f2b(o);
                    } else {
                        Cb[p] = f2b(acc[fr][fc][r]);
                    }
                }
            }
        }
}

// ---------------- gather-GEMM (layer 2): rows from list, grid-stride ----------------
__global__ __launch_bounds__(512) void k_gemm_gather(const u16* __restrict__ A,
                                                     const u16* __restrict__ BT,
                                                     u16* __restrict__ Cb,
                                                     const int* __restrict__ list,
                                                     const int* __restrict__ cnt) {
    __shared__ u16 As[128 * 64];
    __shared__ u16 Bs[256 * 64];

    const int nrows = cnt[0];
    const int tid = threadIdx.x;
    const int w = tid >> 6;
    const int l = tid & 63;
    const int wr = w >> 2;
    const int wc = w & 3;

    const int lr = l >> 3;
    const int lc = l & 7;
    const int src_slot = lc ^ lr;

    for (int m0 = blockIdx.x * 128; m0 < nrows; m0 += gridDim.x * 128) {
        f32x4 acc[4][4] = {};

#pragma unroll
        for (int ks = 0; ks < 4; ++ks) {
            const int k0 = ks * 64;
#pragma unroll
            for (int i = 0; i < 2; ++i) {
                int ridx = m0 + 16 * w + 8 * i + lr;
                ridx = min(ridx, nrows - 1);
                const u16* asrc = A + (size_t)list[ridx] * WIDTH + k0 + src_slot * 8;
                __builtin_amdgcn_global_load_lds(
                    (const __attribute__((address_space(1))) u32*)asrc,
                    (__attribute__((address_space(3))) u32*)(As + (16 * w + 8 * i) * 64), 16, 0, 0);
            }
#pragma unroll
            for (int j = 0; j < 4; ++j) {
                const u16* bsrc = BT + (size_t)(32 * w + 8 * j + lr) * WIDTH + k0 + src_slot * 8;
                __builtin_amdgcn_global_load_lds(
                    (const __attribute__((address_space(1))) u32*)bsrc,
                    (__attribute__((address_space(3))) u32*)(Bs + (32 * w + 8 * j) * 64), 16, 0, 0);
            }
            asm volatile("s_waitcnt vmcnt(0)" ::: "memory");
            __syncthreads();

            bf16x8 a[4][2], b[4][2];
#pragma unroll
            for (int fr = 0; fr < 4; ++fr) {
                const int row = 64 * wr + fr * 16 + (l & 15);
#pragma unroll
                for (int kk = 0; kk < 2; ++kk)
                    a[fr][kk] = *reinterpret_cast<const bf16x8*>(
                        &As[row * 64 + ((kk * 4 + (l >> 4)) ^ (row & 7)) * 8]);
            }
#pragma unroll
            for (int fc = 0; fc < 4; ++fc) {
                const int row = 64 * wc + fc * 16 + (l & 15);
#pragma unroll
                for (int kk = 0; kk < 2; ++kk)
                    b[fc][kk] = *reinterpret_cast<const bf16x8*>(
                        &Bs[row * 64 + ((kk * 4 + (l >> 4)) ^ (row & 7)) * 8]);
            }
#pragma unroll
            for (int fr = 0; fr < 4; ++fr)
#pragma unroll
                for (int fc = 0; fc < 4; ++fc) {
                    acc[fr][fc] = __builtin_amdgcn_mfma_f32_16x16x32_bf16(a[fr][0], b[fc][0], acc[fr][fc], 0, 0, 0);
                    acc[fr][fc] = __builtin_amdgcn_mfma_f32_16x16x32_bf16(a[fr][1], b[fc][1], acc[fr][fc], 0, 0, 0);
                }
            __syncthreads();
        }

        const int r0 = (l >> 4) * 4;
        const int ci = l & 15;
#pragma unroll
        for (int fr = 0; fr < 4; ++fr)
#pragma unroll
            for (int fc = 0; fc < 4; ++fc) {
                const int col = 64 * wc + fc * 16 + ci;
#pragma unroll
                for (int r = 0; r < 4; ++r) {
                    const int row = m0 + 64 * wr + fr * 16 + r0 + r;
                    if (row < nrows)
                        Cb[(size_t)list[row] * WIDTH + col] = f2b(acc[fr][fc][r]);
                }
            }
    }
}

#define EDGE_FMA(vv, dd_)                          \
    acc[0] = fmaf(dd_, b2f_lo(vv.x), acc[0]);      \
    acc[1] = fmaf(dd_, b2f_hi(vv.x), acc[1]);      \
    acc[2] = fmaf(dd_, b2f_lo(vv.y), acc[2]);      \
    acc[3] = fmaf(dd_, b2f_hi(vv.y), acc[3]);

// 32-lane body (layer 0). Writes f32 h only if wflags[node] set (hb always).
__device__ __forceinline__ void agg_node_body(const int* __restrict__ off,
                                              const u32* __restrict__ csr,
                                              const float* __restrict__ dis,
                                              const u16* __restrict__ xlb,
                                              const float* __restrict__ bg,
                                              float* __restrict__ h,
                                              u16* __restrict__ hb,
                                              const int* __restrict__ wflags,
                                              int node, int hl, int ch0) {
    const int c = ch0 + hl * 4;
    const int e0 = off[node];
    const int e1 = off[node + 1];
    const float di = dis[node];

    float acc[4];
    {
        const uint2 v = *reinterpret_cast<const uint2*>(&xlb[(size_t)node * WIDTH + c]);
        acc[0] = di * b2f_lo(v.x);
        acc[1] = di * b2f_hi(v.x);
        acc[2] = di * b2f_lo(v.y);
        acc[3] = di * b2f_hi(v.y);
    }

    for (int base = e0; base < e1; base += 32) {
        const int m = min(32, e1 - base);
        u32 ep = 0;
        if (hl < m) ep = csr[base + hl];
        int j = 0;
        for (; j + 8 <= m; j += 8) {
            uint2 vv[8];
            float dd[8];
#pragma unroll
            for (int q = 0; q < 8; ++q) {
                const u32 e = (u32)__shfl((int)ep, j + q, 32);
                dd[q] = b2f_hi(e);
                vv[q] = *reinterpret_cast<const uint2*>(&xlb[(size_t)(e & 0xffffu) * WIDTH + c]);
            }
#pragma unroll
            for (int q = 0; q < 8; ++q) { EDGE_FMA(vv[q], dd[q]) }
        }
        if (j + 4 <= m) {
            uint2 vv[4];
            float dd[4];
#pragma unroll
            for (int q = 0; q < 4; ++q) {
                const u32 e = (u32)__shfl((int)ep, j + q, 32);
                dd[q] = b2f_hi(e);
                vv[q] = *reinterpret_cast<const uint2*>(&xlb[(size_t)(e & 0xffffu) * WIDTH + c]);
            }
#pragma unroll
            for (int q = 0; q < 4; ++q) { EDGE_FMA(vv[q], dd[q]) }
            j += 4;
        }
        for (; j < m; ++j) {
            const u32 e = (u32)__shfl((int)ep, j, 32);
            const float dj = b2f_hi(e);
            const uint2 v = *reinterpret_cast<const uint2*>(&xlb[(size_t)(e & 0xffffu) * WIDTH + c]);
            EDGE_FMA(v, dj)
        }
    }

    const size_t p = (size_t)node * WIDTH + c;
    const float4 hv = *reinterpret_cast<const float4*>(&h[p]);
    const float4 bv = *reinterpret_cast<const float4*>(&bg[c]);
    const float o0 = hv.x + bv.x + di * acc[0];
    const float o1 = hv.y + bv.y + di * acc[1];
    const float o2 = hv.z + bv.z + di * acc[2];
    const float o3 = hv.w + bv.w + di * acc[3];
    if (wflags == nullptr || wflags[node]) {
        float4 w0;
        w0.x = o0; w0.y = o1; w0.z = o2; w0.w = o3;
        *reinterpret_cast<float4*>(&h[p]) = w0;
    }
    uint2 ob;
    ob.x = pack2(o0, o1);
    ob.y = pack2(o2, o3);
    *reinterpret_cast<uint2*>(&hb[p]) = ob;
}
#undef EDGE_FMA

#define EDGE_FMA16(vv, dd_)                        \
    acc[0] = fmaf(dd_, b2f_lo(vv.x), acc[0]);      \
    acc[1] = fmaf(dd_, b2f_hi(vv.x), acc[1]);      \
    acc[2] = fmaf(dd_, b2f_lo(vv.y), acc[2]);      \
    acc[3] = fmaf(dd_, b2f_hi(vv.y), acc[3]);      \
    acc[4] = fmaf(dd_, b2f_lo(vv.z), acc[4]);      \
    acc[5] = fmaf(dd_, b2f_hi(vv.z), acc[5]);      \
    acc[6] = fmaf(dd_, b2f_lo(vv.w), acc[6]);      \
    acc[7] = fmaf(dd_, b2f_hi(vv.w), acc[7]);

// 16-lane body (list layers): lane owns 8 channels (uint4 = 16B gathers) -> 2x group TLP.
__device__ __forceinline__ void agg_node_body16(const int* __restrict__ off,
                                                const u32* __restrict__ csr,
                                                const float* __restrict__ dis,
                                                const u16* __restrict__ xlb,
                                                const float* __restrict__ bg,
                                                float* __restrict__ h,
                                                u16* __restrict__ hb,
                                                const int* __restrict__ wflags,
                                                int node, int hl, int ch0) {
    const int c = ch0 + hl * 8;
    const int e0 = off[node];
    const int e1 = off[node + 1];
    const float di = dis[node];

    float acc[8];
    {
        const uint4 v = *reinterpret_cast<const uint4*>(&xlb[(size_t)node * WIDTH + c]);
        acc[0] = di * b2f_lo(v.x); acc[1] = di * b2f_hi(v.x);
        acc[2] = di * b2f_lo(v.y); acc[3] = di * b2f_hi(v.y);
        acc[4] = di * b2f_lo(v.z); acc[5] = di * b2f_hi(v.z);
        acc[6] = di * b2f_lo(v.w); acc[7] = di * b2f_hi(v.w);
    }

    for (int base = e0; base < e1; base += 16) {
        const int m = min(16, e1 - base);
        u32 ep = 0;
        if (hl < m) ep = csr[base + hl];
        int j = 0;
        for (; j + 8 <= m; j += 8) {
            uint4 vv[8];
            float dd[8];
#pragma unroll
            for (int q = 0; q < 8; ++q) {
                const u32 e = (u32)__shfl((int)ep, j + q, 16);
                dd[q] = b2f_hi(e);
                vv[q] = *reinterpret_cast<const uint4*>(&xlb[(size_t)(e & 0xffffu) * WIDTH + c]);
            }
#pragma unroll
            for (int q = 0; q < 8; ++q) { EDGE_FMA16(vv[q], dd[q]) }
        }
        if (j + 4 <= m) {
            uint4 vv[4];
            float dd[4];
#pragma unroll
            for (int q = 0; q < 4; ++q) {
                const u32 e = (u32)__shfl((int)ep, j + q, 16);
                dd[q] = b2f_hi(e);
                vv[q] = *reinterpret_cast<const uint4*>(&xlb[(size_t)(e & 0xffffu) * WIDTH + c]);
            }
#pragma unroll
            for (int q = 0; q < 4; ++q) { EDGE_FMA16(vv[q], dd[q]) }
            j += 4;
        }
        for (; j < m; ++j) {
            const u32 e = (u32)__shfl((int)ep, j, 16);
            const float dj = b2f_hi(e);
            const uint4 v = *reinterpret_cast<const uint4*>(&xlb[(size_t)(e & 0xffffu) * WIDTH + c]);
            EDGE_FMA16(v, dj)
        }
    }

    const size_t p = (size_t)node * WIDTH + c;
    const float4 h0 = *reinterpret_cast<const float4*>(&h[p]);
    const float4 h1 = *reinterpret_cast<const float4*>(&h[p + 4]);
    const float4 b0 = *reinterpret_cast<const float4*>(&bg[c]);
    const float4 b1 = *reinterpret_cast<const float4*>(&bg[c + 4]);
    float o[8];
    o[0] = h0.x + b0.x + di * acc[0];
    o[1] = h0.y + b0.y + di * acc[1];
    o[2] = h0.z + b0.z + di * acc[2];
    o[3] = h0.w + b0.w + di * acc[3];
    o[4] = h1.x + b1.x + di * acc[4];
    o[5] = h1.y + b1.y + di * acc[5];
    o[6] = h1.z + b1.z + di * acc[6];
    o[7] = h1.w + b1.w + di * acc[7];
    if (wflags == nullptr || wflags[node]) {
        float4 w0, w1;
        w0.x = o[0]; w0.y = o[1]; w0.z = o[2]; w0.w = o[3];
        w1.x = o[4]; w1.y = o[5]; w1.z = o[6]; w1.w = o[7];
        *reinterpret_cast<float4*>(&h[p]) = w0;
        *reinterpret_cast<float4*>(&h[p + 4]) = w1;
    }
    uint4 ob;
    ob.x = pack2(o[0], o[1]);
    ob.y = pack2(o[2], o[3]);
    ob.z = pack2(o[4], o[5]);
    ob.w = pack2(o[6], o[7]);
    *reinterpret_cast<uint4*>(&hb[p]) = ob;
}
#undef EDGE_FMA16

// ---------------- full aggregate (layer 0): f32 h written only at F2 (flags2) ----------------
__global__ __launch_bounds__(256) void k_agg(const int* __restrict__ off,
                                             const u32* __restrict__ csr,
                                             const float* __restrict__ dis,
                                             const u16* __restrict__ xlb,
                                             const float* __restrict__ bg,
                                             float* __restrict__ h,
                                             u16* __restrict__ hb,
                                             const int* __restrict__ flags2,
                                             int nbh, int N) {
    int bh = blockIdx.x;
    int ch0 = 0;
    if (bh >= nbh) { ch0 = 128; bh -= nbh; }
    const int node = (bh * 256 + threadIdx.x) >> 5;
    if (node >= N) return;
    agg_node_body(off, csr, dis, xlb, bg, h, hb, flags2, node, threadIdx.x & 31, ch0);
}

// ---------------- list aggregate (layers 1,2): 16-lane groups, grid-stride ----------------
__global__ __launch_bounds__(256) void k_agg_list(const int* __restrict__ off,
                                                  const u32* __restrict__ csr,
                                                  const float* __restrict__ dis,
                                                  const u16* __restrict__ xlb,
                                                  const float* __restrict__ bg,
                                                  float* __restrict__ h,
                                                  u16* __restrict__ hb,
                                                  const int* __restrict__ list,
                                                  const int* __restrict__ cnt,
                                                  const int* __restrict__ wflags) {
    const int nitems = cnt[0] * 2;
    const int hl = threadIdx.x & 15;
    const int stride = (gridDim.x * 256) >> 4;
    for (int item = (blockIdx.x * 256 + threadIdx.x) >> 4; item < nitems; item += stride) {
        const int node = list[item >> 1];
        const int ch0 = (item & 1) << 7;
        agg_node_body16(off, csr, dis, xlb, bg, h, hb, wflags, node, hl, ch0);
    }
}

// ---------------- fused tail: last GCN layer at the 32 centers + head ----------------
__global__ __launch_bounds__(256) void k_tail(const int* __restrict__ off,
                                              const u32* __restrict__ csr,
                                              const float* __restrict__ dis,
                                              const u16* __restrict__ hb,
                                              const float* __restrict__ h,
                                              const float* __restrict__ Wg3,
                                              const float* __restrict__ bg3,
                                              const float* __restrict__ Wh,
                                              const float* __restrict__ bh,
                                              const int* __restrict__ center,
                                              const int* __restrict__ ptr,
                                              float* __restrict__ out) {
    __shared__ float aggK[256];
    __shared__ u32 es[256];
    __shared__ float gs[256];
    const int g = blockIdx.x;
    const int t = threadIdx.x;
    const int node = center[g] + ptr[g];
    const int e0 = off[node];
    const int e1 = off[node + 1];
    const float di = dis[node];

    float acc = di * b2fu(hb[(size_t)node * WIDTH + t]);   // self-loop
    for (int base = e0; base < e1; base += 256) {
        const int m = min(256, e1 - base);
        if (t < m) es[t] = csr[base + t];
        __syncthreads();
        int j = 0;
        for (; j + 4 <= m; j += 4) {
            const u32 a0 = es[j + 0], a1 = es[j + 1], a2 = es[j + 2], a3 = es[j + 3];
            const float v0 = b2fu(hb[(size_t)(a0 & 0xffffu) * WIDTH + t]);
            const float v1 = b2fu(hb[(size_t)(a1 & 0xffffu) * WIDTH + t]);
            const float v2 = b2fu(hb[(size_t)(a2 & 0xffffu) * WIDTH + t]);
            const float v3 = b2fu(hb[(size_t)(a3 & 0xffffu) * WIDTH + t]);
            acc = fmaf(b2f_hi(a0), v0, acc);
            acc = fmaf(b2f_hi(a1), v1, acc);
            acc = fmaf(b2f_hi(a2), v2, acc);
            acc = fmaf(b2f_hi(a3), v3, acc);
        }
        for (; j < m; ++j) {
            const u32 a = es[j];
            acc = fmaf(b2f_hi(a), b2fu(hb[(size_t)(a & 0xffffu) * WIDTH + t]), acc);
        }
        __syncthreads();
    }
    aggK[t] = acc;
    __syncthreads();

    float mv = 0.0f;
#pragma unroll 8
    for (int k = 0; k < 256; ++k)
        mv = fmaf(aggK[k], Wg3[(size_t)k * 256 + t], mv);
    const float h4 = h[(size_t)node * WIDTH + t] + bg3[t] + di * mv;
    gs[t] = gelu_exact(h4);
    __syncthreads();
    if (t < 7) {
        float o = bh[t];
        for (int k = 0; k < 256; ++k)
            o = fmaf(gs[k], Wh[t * 256 + k], o);
        out[g * 7 + t] = o;
    }
}

extern "C" void kernel_launch(void* const* d_in, const int* in_sizes, int n_in,
                              void* d_out, int out_size, void* d_ws, size_t ws_size,
                              hipStream_t stream) {
    const float* x      = (const float*)d_in[0];
    const int*   ei     = (const int*)d_in[1];
    const int*   center = (const int*)d_in[2];
    const int*   ptr    = (const int*)d_in[3];
    const float* Wf     = (const float*)d_in[4];
    const float* bf     = (const float*)d_in[5];
    const float* Wg     = (const float*)d_in[6];
    const float* bg     = (const float*)d_in[7];
    const float* Wh     = (const float*)d_in[8];
    const float* bh     = (const float*)d_in[9];

    const int E = in_sizes[1] / 2;       // 799744
    const int N = in_sizes[0] / 64;      // 49984
    const int B = in_sizes[2];           // 32

    char* ws = (char*)d_ws;
    size_t o = 0;
    float* h       = (float*)(ws + o); o += (size_t)N * WIDTH * 4;   // 51.2 MB
    u16*   hb      = (u16*)  (ws + o); o += (size_t)N * WIDTH * 2;   // 25.6 MB
    u16*   xlb     = (u16*)  (ws + o); o += (size_t)N * WIDTH * 2;   // 25.6 MB
    u16*   xb      = (u16*)  (ws + o); o += (size_t)N * 64 * 2;      // 6.4 MB
    float* dis     = (float*)(ws + o); o += (size_t)N * 4;
    int*   deg8    = (int*)  (ws + o); o += (size_t)N * 8 * 4;       // 1.6 MB (8 copies)
    u16*   base8   = (u16*)  (ws + o); o += (size_t)N * 8 * 2;       // 0.8 MB
    int*   off     = (int*)  (ws + o); o += (size_t)(N + 1) * 4;
    int*   part    = (int*)  (ws + o); o += 1024;
    u16*   rank    = (u16*)  (ws + o); o += (size_t)E * 2;           // 1.6 MB
    u32*   csr     = (u32*)  (ws + o); o += (size_t)E * 4;           // 3.2 MB
    u16*   WgT     = (u16*)  (ws + o); o += (size_t)4 * 65536 * 2;   // 0.5 MB
    u16*   WfT     = (u16*)  (ws + o); o += (size_t)256 * 64 * 2;    // 32 KB
    int*   flags   = (int*)  (ws + o); o += (size_t)N * 4;           // F1 flags
    int*   flags2  = (int*)  (ws + o); o += (size_t)N * 4;           // F2 flags
    int*   cnt     = (int*)  (ws + o); o += 128;                     // F1 count
    int*   cnt2    = (int*)  (ws + o); o += 128;                     // F2 count
    int*   list1   = (int*)  (ws + o); o += (size_t)N * 4;           // F1 list
    int*   list2   = (int*)  (ws + o); o += (size_t)N * 4;           // F2 list

    const int* rowv = ei;
    const int* colv = ei + E;

    const int nb = (N + 255) / 256;   // 196
    const int eb = (E + 255) / 256;

    // CSR build
    hipMemsetAsync(deg8, 0, (size_t)N * 8 * 4, stream);
    hipMemsetAsync(flags, 0, (size_t)N * 8 + 256, stream);   // flags | flags2 | cnt | cnt2
    const int total8 = N * 64 / 8;
    const int prep_threads = PREP_WG + PREP_WF + total8;
    k_prep<<<(prep_threads + 255) / 256, 256, 0, stream>>>(Wg, Wf, x, WgT, WfT, xb, total8);
    k_hist8<<<eb, 256, 0, stream>>>(colv, deg8, rank, E, N);
    k_scan1<<<nb, 256, 0, stream>>>(deg8, off, part, dis, base8, N);
    k_scan3<<<nb, 256, 0, stream>>>(off, part, nb, N, E);
    k_fill<<<eb, 256, 0, stream>>>(rowv, colv, rank, base8, dis, off, csr, E, N);
    // frontier lists: F1 = centers U N(centers); F2 = F1 U N(F1)
    k_front<<<B, 256, 0, stream>>>(center, ptr, off, csr, flags, list1, cnt);
    k_front2<<<64, 256, 0, stream>>>(off, csr, list1, cnt, flags2, list2, cnt2);

    // foot: h = gelu(xb @ WfT^T + bf); writes h f32 + hb bf16
    const int gb = (N + 127) / 128;   // 391
    k_gemm_mfma<64, true><<<gb, 512, 0, stream>>>(xb, WfT, bf, hb, h, N);

    // layer 0: full GEMM + full aggregate (f32 h written only at F2)
    const int nbh = N / 8;   // blocks per channel half
    k_gemm_mfma<256, false><<<gb, 512, 0, stream>>>(hb, WgT, nullptr, xlb, nullptr, N);
    k_agg<<<2 * nbh, 256, 0, stream>>>(off, csr, dis, xlb, bg, h, hb, flags2, nbh, N);

    // layer 1: full GEMM, aggregate only at F2 (f32 h written only at F1)
    k_gemm_mfma<256, false><<<gb, 512, 0, stream>>>(hb, WgT + (size_t)1 * 65536, nullptr, xlb, nullptr, N);
    k_agg_list<<<1024, 256, 0, stream>>>(off, csr, dis, xlb, bg + (size_t)1 * WIDTH, h, hb, list2, cnt2, flags);

    // layer 2: gather-GEMM over F2 rows only, aggregate only at F1 (h written everywhere in F1)
    k_gemm_gather<<<128, 512, 0, stream>>>(hb, WgT + (size_t)2 * 65536, xlb, list2, cnt2);
    k_agg_list<<<256, 256, 0, stream>>>(off, csr, dis, xlb, bg + (size_t)2 * WIDTH, h, hb, list1, cnt, nullptr);

    // layer 3 + head fused at the 32 centers
    k_tail<<<B, 256, 0, stream>>>(off, csr, dis, hb, h,
                                  Wg + (size_t)3 * 65536, bg + (size_t)3 * WIDTH,
                                  Wh, bh, center, ptr, (float*)d_out);
}